// Round 2
// baseline (8690.131 us; speedup 1.0000x reference)
//
#include <hip/hip_runtime.h>

#define RES   128
#define EMBD  8
#define HID   128
#define W0F   30.0f
#define SCALE 63.5f   // dx/dpos = 0.5*(RES-1)

__global__ __launch_bounds__(256, 1)
void nsdf_kernel(const float* __restrict__ pos,
                 const float* __restrict__ grid,
                 const float* __restrict__ W0,
                 const float* __restrict__ b0,
                 const float* __restrict__ W1,
                 const float* __restrict__ b1,
                 const float* __restrict__ Wo,
                 const float* __restrict__ bo,
                 float* __restrict__ out, int N)
{
    const int n = blockIdx.x * blockDim.x + threadIdx.x;
    if (n >= N) return;

    const float px = pos[3*n+0], py = pos[3*n+1], pz = pos[3*n+2];

    // ---------------- encode: smoothstep-weighted trilinear ----------------
    const float upper = 126.999992f;  // res-1-1e-6
    float fx = fminf(fmaxf((px + 1.f) * 0.5f * (RES - 1), 0.f), upper);
    float fy = fminf(fmaxf((py + 1.f) * 0.5f * (RES - 1), 0.f), upper);
    float fz = fminf(fmaxf((pz + 1.f) * 0.5f * (RES - 1), 0.f), upper);
    int ix0 = (int)fx, iy0 = (int)fy, iz0 = (int)fz;
    int ix1 = ix0 + 1 < RES - 1 ? ix0 + 1 : RES - 1;
    int iy1 = iy0 + 1 < RES - 1 ? iy0 + 1 : RES - 1;
    int iz1 = iz0 + 1 < RES - 1 ? iz0 + 1 : RES - 1;
    float tx = fx - (float)ix0, ty = fy - (float)iy0, tz = fz - (float)iz0;
    float wx = tx * tx * (3.f - 2.f * tx);
    float wy = ty * ty * (3.f - 2.f * ty);
    float wz = tz * tz * (3.f - 2.f * tz);
    float dwx = 6.f * tx * (1.f - tx) * SCALE;
    float dwy = 6.f * ty * (1.f - ty) * SCALE;
    float dwz = 6.f * tz * (1.f - tz) * SCALE;

    const float4* g4 = (const float4*)grid;
    // float4-unit index of corner (ix,iy,iz): ((ix*RES+iy)*RES+iz)*EMBD/4
    int b000 = ((ix0 * RES + iy0) * RES + iz0) * 2;
    int b001 = ((ix0 * RES + iy0) * RES + iz1) * 2;
    int b010 = ((ix0 * RES + iy1) * RES + iz0) * 2;
    int b011 = ((ix0 * RES + iy1) * RES + iz1) * 2;
    int b100 = ((ix1 * RES + iy0) * RES + iz0) * 2;
    int b101 = ((ix1 * RES + iy0) * RES + iz1) * 2;
    int b110 = ((ix1 * RES + iy1) * RES + iz0) * 2;
    int b111 = ((ix1 * RES + iy1) * RES + iz1) * 2;

    float c000[8], c001[8], c010[8], c011[8], c100[8], c101[8], c110[8], c111[8];
    *(float4*)&c000[0] = g4[b000]; *(float4*)&c000[4] = g4[b000 + 1];
    *(float4*)&c001[0] = g4[b001]; *(float4*)&c001[4] = g4[b001 + 1];
    *(float4*)&c010[0] = g4[b010]; *(float4*)&c010[4] = g4[b010 + 1];
    *(float4*)&c011[0] = g4[b011]; *(float4*)&c011[4] = g4[b011 + 1];
    *(float4*)&c100[0] = g4[b100]; *(float4*)&c100[4] = g4[b100 + 1];
    *(float4*)&c101[0] = g4[b101]; *(float4*)&c101[4] = g4[b101 + 1];
    *(float4*)&c110[0] = g4[b110]; *(float4*)&c110[4] = g4[b110 + 1];
    *(float4*)&c111[0] = g4[b111]; *(float4*)&c111[4] = g4[b111 + 1];

    float emb[8], dex[8], dey[8], dez[8];
#pragma unroll
    for (int k = 0; k < 8; ++k) {
        float a000 = c000[k], a001 = c001[k], a010 = c010[k], a011 = c011[k];
        float a100 = c100[k], a101 = c101[k], a110 = c110[k], a111 = c111[k];
        float dX00 = a100 - a000, dX10 = a110 - a010;
        float dX01 = a101 - a001, dX11 = a111 - a011;
        float c00 = a000 + dX00 * wx;   // y0 z0
        float c10 = a010 + dX10 * wx;   // y1 z0
        float c01 = a001 + dX01 * wx;   // y0 z1
        float c11 = a011 + dX11 * wx;   // y1 z1
        float cy0 = c00 + (c10 - c00) * wy;
        float cy1 = c01 + (c11 - c01) * wy;
        emb[k] = cy0 + (cy1 - cy0) * wz;
        dez[k] = (cy1 - cy0) * dwz;
        float dy0 = c10 - c00, dy1 = c11 - c01;
        dey[k] = (dy0 + (dy1 - dy0) * wz) * dwy;
        float dx0 = dX00 + (dX10 - dX00) * wy;
        float dx1 = dX01 + (dX11 - dX01) * wy;
        dex[k] = (dx0 + (dx1 - dx0) * wz) * dwx;
    }

    // ---------------- layer 1: 11 -> 128, h1 = sin(30*(h@W0+b0)) ----------
    float h1[HID];
    unsigned int sgn[4] = {0u, 0u, 0u, 0u};  // sign of cos(30*pre1_j)
#pragma unroll
    for (int j = 0; j < HID; ++j) {
        float a = b0[j];
#pragma unroll
        for (int k = 0; k < 8; ++k) a += emb[k] * W0[k * HID + j];
        a += px * W0[8 * HID + j];
        a += py * W0[9 * HID + j];
        a += pz * W0[10 * HID + j];
        float s, c;
        __sincosf(W0F * a, &s, &c);
        h1[j] = s;
        sgn[j >> 5] |= (__float_as_uint(c) >> 31) << (j & 31);
    }

    // ---------------- layer 2 fwd + output + layer-2 bwd (interleaved) ----
    float dh1[HID];
#pragma unroll
    for (int j = 0; j < HID; ++j) dh1[j] = 0.f;
    float sdf = bo[0];

#pragma unroll 1
    for (int i = 0; i < HID; i += 4) {
        float a0 = b1[i + 0], a1 = b1[i + 1], a2 = b1[i + 2], a3 = b1[i + 3];
#pragma unroll
        for (int j = 0; j < HID; ++j) {
            const float hj = h1[j];
            const float4 w = *(const float4*)&W1[j * HID + i];  // uniform -> s_load
            a0 += hj * w.x; a1 += hj * w.y; a2 += hj * w.z; a3 += hj * w.w;
        }
        float v0, v1, v2, v3;
        {
            float s, c, wo;
            wo = Wo[i + 0]; __sincosf(W0F * a0, &s, &c); sdf += wo * s; v0 = W0F * c * wo;
            wo = Wo[i + 1]; __sincosf(W0F * a1, &s, &c); sdf += wo * s; v1 = W0F * c * wo;
            wo = Wo[i + 2]; __sincosf(W0F * a2, &s, &c); sdf += wo * s; v2 = W0F * c * wo;
            wo = Wo[i + 3]; __sincosf(W0F * a3, &s, &c); sdf += wo * s; v3 = W0F * c * wo;
        }
#pragma unroll
        for (int j = 0; j < HID; ++j) {
            const float4 w = *(const float4*)&W1[j * HID + i];  // same quad, sK$-hit
            dh1[j] += v0 * w.x + v1 * w.y + v2 * w.z + v3 * w.w;
        }
    }

    // ---------------- layer-1 backward + input grads ----------------------
    float dh[11];
#pragma unroll
    for (int k = 0; k < 11; ++k) dh[k] = 0.f;
#pragma unroll
    for (int j = 0; j < HID; ++j) {
        float s = h1[j];
        float c = sqrtf(fmaxf(0.f, 1.f - s * s));
        unsigned int sb = (sgn[j >> 5] >> (j & 31)) & 1u;
        c = __uint_as_float(__float_as_uint(c) | (sb << 31));
        float dp = W0F * c * dh1[j];
#pragma unroll
        for (int k = 0; k < 11; ++k) dh[k] += dp * W0[k * HID + j];
    }

    float gx = dh[8], gy = dh[9], gz = dh[10];
#pragma unroll
    for (int k = 0; k < 8; ++k) {
        gx += dex[k] * dh[k];
        gy += dey[k] * dh[k];
        gz += dez[k] * dh[k];
    }

    out[n] = sdf;
    out[N + 3 * n + 0] = gx;
    out[N + 3 * n + 1] = gy;
    out[N + 3 * n + 2] = gz;
}

extern "C" void kernel_launch(void* const* d_in, const int* in_sizes, int n_in,
                              void* d_out, int out_size, void* d_ws, size_t ws_size,
                              hipStream_t stream) {
    const float* pos  = (const float*)d_in[0];
    const float* grid = (const float*)d_in[1];
    const float* W0   = (const float*)d_in[2];
    const float* b0   = (const float*)d_in[3];
    const float* W1   = (const float*)d_in[4];
    const float* b1   = (const float*)d_in[5];
    const float* Wo   = (const float*)d_in[6];
    const float* bo   = (const float*)d_in[7];
    float* out = (float*)d_out;
    const int N = in_sizes[0] / 3;
    const int block = 256;
    const int gridsz = (N + block - 1) / block;
    nsdf_kernel<<<gridsz, block, 0, stream>>>(pos, grid, W0, b0, W1, b1, Wo, bo, out, N);
}

// Round 3
// 7537.267 us; speedup vs baseline: 1.1530x; 1.1530x over previous
//
#include <hip/hip_runtime.h>

#define RES 128
#define HID 128
#define W0F 30.0f
#define SCALE 63.5f   // dx/dpos = 0.5*(RES-1)

// bf16 pair pack/unpack (RNE). lo = a, hi = b.
__device__ __forceinline__ unsigned pk2(float a, float b) {
    unsigned ua = __float_as_uint(a), ub = __float_as_uint(b);
    ua = (ua + 0x7fffu + ((ua >> 16) & 1u)) >> 16;
    ub = (ub + 0x7fffu + ((ub >> 16) & 1u)) & 0xffff0000u;
    return ua | ub;
}
__device__ __forceinline__ float lo2(unsigned p) { return __uint_as_float(p << 16); }
__device__ __forceinline__ float hi2(unsigned p) { return __uint_as_float(p & 0xffff0000u); }

__global__ __launch_bounds__(256, 2)
void nsdf_kernel(const float* __restrict__ pos, const float* __restrict__ grid,
                 const float* __restrict__ W0, const float* __restrict__ b0,
                 const float* __restrict__ W1, const float* __restrict__ b1,
                 const float* __restrict__ Wo, const float* __restrict__ bo,
                 float* __restrict__ out, int N)
{
    __shared__ float sW1[HID * HID];   // 64 KB, [j][i] row-major
    __shared__ float sW0t[HID * 12];   // 6 KB, [j][k] transposed, k padded to 12
    __shared__ float sB0[HID];
    __shared__ float sB1[HID];
    __shared__ float sWo[HID];

    const int tid = threadIdx.x;
    const int n = blockIdx.x * blockDim.x + tid;

    // position load first so its latency hides under weight staging
    float px = 0.f, py = 0.f, pz = 0.f;
    if (n < N) { px = pos[3 * n]; py = pos[3 * n + 1]; pz = pos[3 * n + 2]; }

    // ---------------- stage weights to LDS ----------------
    {
        const float4* s4 = (const float4*)W1;
        float4* d4 = (float4*)sW1;
#pragma unroll
        for (int k = 0; k < 16; ++k) d4[tid + k * 256] = s4[tid + k * 256];
        if (tid < HID) {
            sB0[tid] = b0[tid];
            sB1[tid] = b1[tid];
            sWo[tid] = Wo[tid];
#pragma unroll
            for (int k = 0; k < 11; ++k) sW0t[tid * 12 + k] = W0[k * HID + tid];
            sW0t[tid * 12 + 11] = 0.f;
        }
    }
    __syncthreads();

    // ---------------- encode: smoothstep trilinear + Jacobian ----------------
    const float upper = 126.999992f;
    float fx = fminf(fmaxf((px + 1.f) * 0.5f * (RES - 1), 0.f), upper);
    float fy = fminf(fmaxf((py + 1.f) * 0.5f * (RES - 1), 0.f), upper);
    float fz = fminf(fmaxf((pz + 1.f) * 0.5f * (RES - 1), 0.f), upper);
    int ix0 = (int)fx, iy0 = (int)fy, iz0 = (int)fz;   // <= 126, so i1 = i0+1
    float tx = fx - (float)ix0, ty = fy - (float)iy0, tz = fz - (float)iz0;
    float wx = tx * tx * (3.f - 2.f * tx);
    float wy = ty * ty * (3.f - 2.f * ty);
    float wz = tz * tz * (3.f - 2.f * tz);
    float dwx = 6.f * tx * (1.f - tx) * SCALE;
    float dwy = 6.f * ty * (1.f - ty) * SCALE;
    float dwz = 6.f * tz * (1.f - tz) * SCALE;

    const float4* g4 = (const float4*)grid;
    int b000 = ((ix0 * RES + iy0) * RES + iz0) * 2;
    int b010 = ((ix0 * RES + (iy0 + 1)) * RES + iz0) * 2;
    int b100 = (((ix0 + 1) * RES + iy0) * RES + iz0) * 2;
    int b110 = (((ix0 + 1) * RES + (iy0 + 1)) * RES + iz0) * 2;

    float c000[8], c001[8], c010[8], c011[8], c100[8], c101[8], c110[8], c111[8];
    *(float4*)&c000[0] = g4[b000];     *(float4*)&c000[4] = g4[b000 + 1];
    *(float4*)&c001[0] = g4[b000 + 2]; *(float4*)&c001[4] = g4[b000 + 3];
    *(float4*)&c010[0] = g4[b010];     *(float4*)&c010[4] = g4[b010 + 1];
    *(float4*)&c011[0] = g4[b010 + 2]; *(float4*)&c011[4] = g4[b010 + 3];
    *(float4*)&c100[0] = g4[b100];     *(float4*)&c100[4] = g4[b100 + 1];
    *(float4*)&c101[0] = g4[b100 + 2]; *(float4*)&c101[4] = g4[b100 + 3];
    *(float4*)&c110[0] = g4[b110];     *(float4*)&c110[4] = g4[b110 + 1];
    *(float4*)&c111[0] = g4[b110 + 2]; *(float4*)&c111[4] = g4[b110 + 3];

    float emb[8];
    unsigned dexp[4], deyp[4], dezp[4];   // packed bf16 Jacobian
#pragma unroll
    for (int k = 0; k < 8; k += 2) {
        float ex[2], ey[2], ez[2];
#pragma unroll
        for (int q = 0; q < 2; ++q) {
            int kk = k + q;
            float a000 = c000[kk], a001 = c001[kk], a010 = c010[kk], a011 = c011[kk];
            float a100 = c100[kk], a101 = c101[kk], a110 = c110[kk], a111 = c111[kk];
            float dX00 = a100 - a000, dX10 = a110 - a010;
            float dX01 = a101 - a001, dX11 = a111 - a011;
            float c00 = a000 + dX00 * wx;
            float c10 = a010 + dX10 * wx;
            float c01 = a001 + dX01 * wx;
            float c11 = a011 + dX11 * wx;
            float cy0 = c00 + (c10 - c00) * wy;
            float cy1 = c01 + (c11 - c01) * wy;
            emb[kk] = cy0 + (cy1 - cy0) * wz;
            ez[q] = (cy1 - cy0) * dwz;
            float dy0 = c10 - c00, dy1 = c11 - c01;
            ey[q] = (dy0 + (dy1 - dy0) * wz) * dwy;
            float dx0 = dX00 + (dX10 - dX00) * wy;
            float dx1 = dX01 + (dX11 - dX01) * wy;
            ex[q] = (dx0 + (dx1 - dx0) * wz) * dwx;
        }
        dexp[k >> 1] = pk2(ex[0], ex[1]);
        deyp[k >> 1] = pk2(ey[0], ey[1]);
        dezp[k >> 1] = pk2(ez[0], ez[1]);
    }

    // ---------------- layer 1: h1 = sin(30*(x@W0+b0)), bf16-packed --------
    unsigned h1p[64];
    unsigned sgn[4] = {0u, 0u, 0u, 0u};
#pragma unroll
    for (int j = 0; j < HID; j += 2) {
        const float4* wv = (const float4*)&sW0t[j * 12];
        float4 wa = wv[0], wb = wv[1], wc = wv[2];
        float4 xa = wv[3], xb = wv[4], xc = wv[5];
        float a0 = sB0[j]
                 + emb[0] * wa.x + emb[1] * wa.y + emb[2] * wa.z + emb[3] * wa.w
                 + emb[4] * wb.x + emb[5] * wb.y + emb[6] * wb.z + emb[7] * wb.w
                 + px * wc.x + py * wc.y + pz * wc.z;
        float a1 = sB0[j + 1]
                 + emb[0] * xa.x + emb[1] * xa.y + emb[2] * xa.z + emb[3] * xa.w
                 + emb[4] * xb.x + emb[5] * xb.y + emb[6] * xb.z + emb[7] * xb.w
                 + px * xc.x + py * xc.y + pz * xc.z;
        float s0, c0, s1, c1;
        __sincosf(W0F * a0, &s0, &c0);
        __sincosf(W0F * a1, &s1, &c1);
        h1p[j >> 1] = pk2(s0, s1);
        sgn[j >> 5] |= ((__float_as_uint(c0) >> 31) << (j & 31))
                     | ((__float_as_uint(c1) >> 31) << ((j + 1) & 31));
    }

    // ---------------- layer 2 fwd + out + layer-2 bwd, 8 cols per step ----
    float dh1[HID];
#pragma unroll
    for (int j = 0; j < HID; ++j) dh1[j] = 0.f;
    float sdf = bo[0];

#pragma unroll 1
    for (int i = 0; i < HID; i += 8) {
        float acc[8];
#pragma unroll
        for (int u = 0; u < 8; ++u) acc[u] = sB1[i + u];
#pragma unroll
        for (int j = 0; j < HID; j += 2) {
            unsigned hp = h1p[j >> 1];
            float hA = lo2(hp), hB = hi2(hp);
            const float4* wr = (const float4*)&sW1[j * HID + i];
            float4 r0 = wr[0], r1 = wr[1];
            const float4* ws = (const float4*)&sW1[(j + 1) * HID + i];
            float4 t0 = ws[0], t1 = ws[1];
            acc[0] += hA * r0.x; acc[1] += hA * r0.y; acc[2] += hA * r0.z; acc[3] += hA * r0.w;
            acc[4] += hA * r1.x; acc[5] += hA * r1.y; acc[6] += hA * r1.z; acc[7] += hA * r1.w;
            acc[0] += hB * t0.x; acc[1] += hB * t0.y; acc[2] += hB * t0.z; acc[3] += hB * t0.w;
            acc[4] += hB * t1.x; acc[5] += hB * t1.y; acc[6] += hB * t1.z; acc[7] += hB * t1.w;
        }
        float v[8];
#pragma unroll
        for (int u = 0; u < 8; ++u) {
            float s, c;
            __sincosf(W0F * acc[u], &s, &c);
            float wo = sWo[i + u];
            sdf += wo * s;
            v[u] = W0F * c * wo;
        }
        // backward re-read of the same quads: opaque offset defeats GVN/CSE
#pragma unroll
        for (int j = 0; j < HID; ++j) {
            unsigned off = (unsigned)((j * HID + i) * sizeof(float));
            asm volatile("" : "+v"(off));
            const float4* wr = (const float4*)((const char*)sW1 + off);
            float4 r0 = wr[0], r1 = wr[1];
            dh1[j] += v[0] * r0.x + v[1] * r0.y + v[2] * r0.z + v[3] * r0.w
                    + v[4] * r1.x + v[5] * r1.y + v[6] * r1.z + v[7] * r1.w;
        }
    }

    // ---------------- layer-1 backward + input grads ----------------------
    float dh[11];
#pragma unroll
    for (int k = 0; k < 11; ++k) dh[k] = 0.f;
#pragma unroll
    for (int j = 0; j < HID; j += 2) {
        unsigned hp = h1p[j >> 1];
        float s0 = lo2(hp), s1 = hi2(hp);
        float c0 = sqrtf(fmaxf(0.f, 1.f - s0 * s0));
        float c1 = sqrtf(fmaxf(0.f, 1.f - s1 * s1));
        c0 = __uint_as_float(__float_as_uint(c0) | (((sgn[j >> 5] >> (j & 31)) & 1u) << 31));
        c1 = __uint_as_float(__float_as_uint(c1) | (((sgn[j >> 5] >> ((j + 1) & 31)) & 1u) << 31));
        float dp0 = W0F * c0 * dh1[j];
        float dp1 = W0F * c1 * dh1[j + 1];
        unsigned off = (unsigned)(j * 12 * sizeof(float));
        asm volatile("" : "+v"(off));
        const float4* wv = (const float4*)((const char*)sW0t + off);
        float4 wa = wv[0], wb = wv[1], wc = wv[2];
        float4 xa = wv[3], xb = wv[4], xc = wv[5];
        dh[0]  += dp0 * wa.x + dp1 * xa.x;
        dh[1]  += dp0 * wa.y + dp1 * xa.y;
        dh[2]  += dp0 * wa.z + dp1 * xa.z;
        dh[3]  += dp0 * wa.w + dp1 * xa.w;
        dh[4]  += dp0 * wb.x + dp1 * xb.x;
        dh[5]  += dp0 * wb.y + dp1 * xb.y;
        dh[6]  += dp0 * wb.z + dp1 * xb.z;
        dh[7]  += dp0 * wb.w + dp1 * xb.w;
        dh[8]  += dp0 * wc.x + dp1 * xc.x;
        dh[9]  += dp0 * wc.y + dp1 * xc.y;
        dh[10] += dp0 * wc.z + dp1 * xc.z;
    }

    float gx = dh[8], gy = dh[9], gz = dh[10];
#pragma unroll
    for (int k = 0; k < 8; k += 2) {
        unsigned ex = dexp[k >> 1], ey = deyp[k >> 1], ez = dezp[k >> 1];
        gx += lo2(ex) * dh[k] + hi2(ex) * dh[k + 1];
        gy += lo2(ey) * dh[k] + hi2(ey) * dh[k + 1];
        gz += lo2(ez) * dh[k] + hi2(ez) * dh[k + 1];
    }

    if (n < N) {
        out[n] = sdf;
        out[N + 3 * n + 0] = gx;
        out[N + 3 * n + 1] = gy;
        out[N + 3 * n + 2] = gz;
    }
}

extern "C" void kernel_launch(void* const* d_in, const int* in_sizes, int n_in,
                              void* d_out, int out_size, void* d_ws, size_t ws_size,
                              hipStream_t stream) {
    const float* pos  = (const float*)d_in[0];
    const float* grid = (const float*)d_in[1];
    const float* W0   = (const float*)d_in[2];
    const float* b0   = (const float*)d_in[3];
    const float* W1   = (const float*)d_in[4];
    const float* b1   = (const float*)d_in[5];
    const float* Wo   = (const float*)d_in[6];
    const float* bo   = (const float*)d_in[7];
    float* out = (float*)d_out;
    const int N = in_sizes[0] / 3;
    const int block = 256;
    const int gridsz = (N + block - 1) / block;
    nsdf_kernel<<<gridsz, block, 0, stream>>>(pos, grid, W0, b0, W1, b1, Wo, bo, out, N);
}

// Round 4
// 1075.887 us; speedup vs baseline: 8.0772x; 7.0056x over previous
//
#include <hip/hip_runtime.h>

#define RES 128
#define HID 128
#define W0F 30.0f
#define SCALE 63.5f

typedef __bf16 bf16x8 __attribute__((ext_vector_type(8)));
typedef float f32x4 __attribute__((ext_vector_type(4)));

__device__ __forceinline__ unsigned short bf16rne(float x) {
    unsigned u = __float_as_uint(x);
    u = (u + 0x7fffu + ((u >> 16) & 1u)) >> 16;
    return (unsigned short)u;
}
__device__ __forceinline__ unsigned pk2f(float a, float b) {
    return (unsigned)bf16rne(a) | ((unsigned)bf16rne(b) << 16);
}
__device__ __forceinline__ float lo2(unsigned p) { return __uint_as_float(p << 16); }
__device__ __forceinline__ float hi2(unsigned p) { return __uint_as_float(p & 0xffff0000u); }

// ---- prep: W1 fp32 -> two fragment-ordered bf16 copies in d_ws ----
// layout: ws[(tile*64 + lane)*8 + e]; tile = hi16*4 + ks
//   copy0 (colT, for GEMM1 B: k=j): value = W1[ks*32+(lane>>4)*8+e][hi16*16+(lane&15)]
//   copy1 (row,  for GEMM2 B: k=i): value = W1[hi16*16+(lane&15)][ks*32+(lane>>4)*8+e]
__global__ void prep_kernel(const float* __restrict__ W1, unsigned short* __restrict__ ws) {
    int t = blockIdx.x * blockDim.x + threadIdx.x;   // 0..16383
    int tile = t >> 9;
    int lane = (t >> 3) & 63;
    int e = t & 7;
    int hi16 = tile >> 2;
    int ks = tile & 3;
    int koff = ks * 32 + (lane >> 4) * 8 + e;
    int noff = hi16 * 16 + (lane & 15);
    ws[t] = bf16rne(W1[koff * HID + noff]);
    ws[16384 + t] = bf16rne(W1[noff * HID + koff]);
}

__global__ __launch_bounds__(256)
void nsdf_main(const float* __restrict__ pos, const float* __restrict__ grid,
               const float* __restrict__ W0, const float* __restrict__ b0,
               const float* __restrict__ b1, const float* __restrict__ Wo,
               const float* __restrict__ bo, const unsigned short* __restrict__ wfrag,
               float* __restrict__ out, int N)
{
    __shared__ unsigned short sBuf[4 * 8192];   // 64 KB: one 16 KB wave-private region each
    __shared__ float sW0t[HID * 12];            // [j][k], k padded to 12
    __shared__ float sB0[HID], sB1v[HID], sWov[HID];
    __shared__ float sBo;

    const int tid = threadIdx.x;
    const int l = tid & 63;
    const int wid = tid >> 6;
    const int low = l & 15;
    const int lk = l >> 4;
    const int wb = wid * 16384;   // byte base of this wave's region
    const int mloc = l;           // local point index within wave

    // ---- stage small weights (overlaps with encode's global gather) ----
    if (tid < HID) {
        sB0[tid] = b0[tid];
        sB1v[tid] = b1[tid];
        sWov[tid] = Wo[tid];
#pragma unroll
        for (int k = 0; k < 11; ++k) sW0t[tid * 12 + k] = W0[k * HID + tid];
        sW0t[tid * 12 + 11] = 0.f;
    }
    if (tid == 0) sBo = bo[0];

    const int n = blockIdx.x * 256 + tid;
    const float px = pos[3 * n], py = pos[3 * n + 1], pz = pos[3 * n + 2];

    // ---- encode: smoothstep trilinear + Jacobian ----
    const float upper = 126.999992f;
    float fx = fminf(fmaxf((px + 1.f) * 0.5f * (RES - 1), 0.f), upper);
    float fy = fminf(fmaxf((py + 1.f) * 0.5f * (RES - 1), 0.f), upper);
    float fz = fminf(fmaxf((pz + 1.f) * 0.5f * (RES - 1), 0.f), upper);
    int ix0 = (int)fx, iy0 = (int)fy, iz0 = (int)fz;
    float tx = fx - (float)ix0, ty = fy - (float)iy0, tz = fz - (float)iz0;
    float wx = tx * tx * (3.f - 2.f * tx);
    float wy = ty * ty * (3.f - 2.f * ty);
    float wz = tz * tz * (3.f - 2.f * tz);
    float dwx = 6.f * tx * (1.f - tx) * SCALE;
    float dwy = 6.f * ty * (1.f - ty) * SCALE;
    float dwz = 6.f * tz * (1.f - tz) * SCALE;

    const float4* g4 = (const float4*)grid;
    int b000 = ((ix0 * RES + iy0) * RES + iz0) * 2;
    int b010 = ((ix0 * RES + (iy0 + 1)) * RES + iz0) * 2;
    int b100 = (((ix0 + 1) * RES + iy0) * RES + iz0) * 2;
    int b110 = (((ix0 + 1) * RES + (iy0 + 1)) * RES + iz0) * 2;

    float c000[8], c001[8], c010[8], c011[8], c100[8], c101[8], c110[8], c111[8];
    *(float4*)&c000[0] = g4[b000];     *(float4*)&c000[4] = g4[b000 + 1];
    *(float4*)&c001[0] = g4[b000 + 2]; *(float4*)&c001[4] = g4[b000 + 3];
    *(float4*)&c010[0] = g4[b010];     *(float4*)&c010[4] = g4[b010 + 1];
    *(float4*)&c011[0] = g4[b010 + 2]; *(float4*)&c011[4] = g4[b010 + 3];
    *(float4*)&c100[0] = g4[b100];     *(float4*)&c100[4] = g4[b100 + 1];
    *(float4*)&c101[0] = g4[b100 + 2]; *(float4*)&c101[4] = g4[b100 + 3];
    *(float4*)&c110[0] = g4[b110];     *(float4*)&c110[4] = g4[b110 + 1];
    *(float4*)&c111[0] = g4[b110 + 2]; *(float4*)&c111[4] = g4[b110 + 3];

    unsigned embp[4], jxp[4], jyp[4], jzp[4];   // packed bf16: emb + Jacobian
#pragma unroll
    for (int k = 0; k < 8; k += 2) {
        float em[2], ex[2], ey[2], ez[2];
#pragma unroll
        for (int qq = 0; qq < 2; ++qq) {
            int kk = k + qq;
            float a000 = c000[kk], a001 = c001[kk], a010 = c010[kk], a011 = c011[kk];
            float a100 = c100[kk], a101 = c101[kk], a110 = c110[kk], a111 = c111[kk];
            float dX00 = a100 - a000, dX10 = a110 - a010;
            float dX01 = a101 - a001, dX11 = a111 - a011;
            float c00 = a000 + dX00 * wx;
            float c10 = a010 + dX10 * wx;
            float c01 = a001 + dX01 * wx;
            float c11 = a011 + dX11 * wx;
            float cy0 = c00 + (c10 - c00) * wy;
            float cy1 = c01 + (c11 - c01) * wy;
            em[qq] = cy0 + (cy1 - cy0) * wz;
            ez[qq] = (cy1 - cy0) * dwz;
            float dy0 = c10 - c00, dy1 = c11 - c01;
            ey[qq] = (dy0 + (dy1 - dy0) * wz) * dwy;
            float dx0 = dX00 + (dX10 - dX00) * wy;
            float dx1 = dX01 + (dX11 - dX01) * wy;
            ex[qq] = (dx0 + (dx1 - dx0) * wz) * dwx;
        }
        embp[k >> 1] = pk2f(em[0], em[1]);
        jxp[k >> 1] = pk2f(ex[0], ex[1]);
        jyp[k >> 1] = pk2f(ey[0], ey[1]);
        jzp[k >> 1] = pk2f(ez[0], ez[1]);
    }

    float xe[8];
#pragma unroll
    for (int k = 0; k < 4; ++k) { xe[2 * k] = lo2(embp[k]); xe[2 * k + 1] = hi2(embp[k]); }

    __syncthreads();

    // ---- layer 1 fwd (per-thread): h1 = sin(30*pre1) -> A1-frag-ordered LDS ----
    const int q15 = mloc & 15, mtOwn = mloc >> 4;
#pragma unroll
    for (int o = 0; o < 16; ++o) {
        float sv[8];
#pragma unroll
        for (int jj = 0; jj < 8; ++jj) {
            int j = o * 8 + jj;
            const float4* wr = (const float4*)&sW0t[j * 12];
            float4 wa = wr[0], wbq = wr[1], wc = wr[2];
            float a = sB0[j]
                + xe[0] * wa.x + xe[1] * wa.y + xe[2] * wa.z + xe[3] * wa.w
                + xe[4] * wbq.x + xe[5] * wbq.y + xe[6] * wbq.z + xe[7] * wbq.w
                + px * wc.x + py * wc.y + pz * wc.z;
            sv[jj] = __sinf(W0F * a);
        }
        uint4 w4;
        w4.x = pk2f(sv[0], sv[1]); w4.y = pk2f(sv[2], sv[3]);
        w4.z = pk2f(sv[4], sv[5]); w4.w = pk2f(sv[6], sv[7]);
        int byte = wb + (o >> 2) * 4096 + q15 * 256 + mtOwn * 64 + (o & 3) * 16;
        byte ^= (mloc & 7) << 4;
        *(uint4*)&sBuf[byte >> 1] = w4;
    }

    // ---- GEMM1: pre2 = h1 @ W1 (M=64/wave, N=128, K=128) ----
    uint4 A1[4][4];
#pragma unroll
    for (int mt = 0; mt < 4; ++mt)
#pragma unroll
        for (int js = 0; js < 4; ++js) {
            int byte = wb + js * 4096 + low * 256 + mt * 64 + lk * 16;
            byte ^= (low & 7) << 4;
            A1[mt][js] = *(const uint4*)&sBuf[byte >> 1];
        }

    const uint4* wct = (const uint4*)wfrag;             // colT frags (GEMM1 B)
    const uint4* wrw = (const uint4*)(wfrag + 16384);   // row frags (GEMM2 B)

    float sdfp[4][4];
#pragma unroll
    for (int a = 0; a < 4; ++a)
#pragma unroll
        for (int b = 0; b < 4; ++b) sdfp[a][b] = 0.f;

#pragma unroll
    for (int h = 0; h < 2; ++h) {
        f32x4 c1[4][4];
#pragma unroll
        for (int mt = 0; mt < 4; ++mt)
#pragma unroll
            for (int u = 0; u < 4; ++u) c1[mt][u] = (f32x4){0.f, 0.f, 0.f, 0.f};
#pragma unroll
        for (int ntL = 0; ntL < 4; ++ntL) {
            int nt = h * 4 + ntL;
            uint4 Bf[4];
#pragma unroll
            for (int js = 0; js < 4; ++js) Bf[js] = wct[(nt * 4 + js) * 64 + l];
#pragma unroll
            for (int mt = 0; mt < 4; ++mt)
#pragma unroll
                for (int js = 0; js < 4; ++js)
                    c1[mt][ntL] = __builtin_amdgcn_mfma_f32_16x16x32_bf16(
                        __builtin_bit_cast(bf16x8, A1[mt][js]),
                        __builtin_bit_cast(bf16x8, Bf[js]), c1[mt][ntL], 0, 0, 0);
        }
        // v-phase: sincos on C1, accumulate sdf, scatter v (bf16) into A2-frag order
#pragma unroll
        for (int ntL = 0; ntL < 4; ++ntL) {
            int nt = h * 4 + ntL;
            int i = nt * 16 + low;
            float b1e = sB1v[i], woe = sWov[i];
            int istep = nt >> 1;
            int i32 = (nt & 1) * 16 + low;
            int ibyte = (i32 >> 3) * 16 + (i32 & 7) * 2;
#pragma unroll
            for (int mt = 0; mt < 4; ++mt)
#pragma unroll
                for (int r = 0; r < 4; ++r) {
                    float pre = c1[mt][ntL][r] + b1e;
                    float s, c;
                    __sincosf(W0F * pre, &s, &c);
                    sdfp[mt][r] += woe * s;
                    float v = W0F * c * woe;
                    int q = lk * 4 + r;
                    int byte = wb + istep * 4096 + q * 256 + mt * 64 + ibyte;
                    byte ^= (q & 7) << 4;
                    sBuf[byte >> 1] = bf16rne(v);
                }
        }
    }

    // ---- sdf reduce (over 16 lanes sharing i-range) + store ----
    {
        int blkBase = blockIdx.x * 256 + wid * 64;
        float boV = sBo;
#pragma unroll
        for (int mt = 0; mt < 4; ++mt)
#pragma unroll
            for (int r = 0; r < 4; ++r) {
                float sv = sdfp[mt][r];
                sv += __shfl_xor(sv, 1);
                sv += __shfl_xor(sv, 2);
                sv += __shfl_xor(sv, 4);
                sv += __shfl_xor(sv, 8);
                if (low == 0) out[blkBase + mt * 16 + lk * 4 + r] = sv + boV;
            }
    }

    // ---- GEMM2: dh1 = v @ W1^T ----
    uint4 A2[4][4];
#pragma unroll
    for (int mt = 0; mt < 4; ++mt)
#pragma unroll
        for (int is = 0; is < 4; ++is) {
            int byte = wb + is * 4096 + low * 256 + mt * 64 + lk * 16;
            byte ^= (low & 7) << 4;
            A2[mt][is] = *(const uint4*)&sBuf[byte >> 1];
        }

#pragma unroll
    for (int h = 0; h < 2; ++h) {
        f32x4 c2[4][4];
#pragma unroll
        for (int mt = 0; mt < 4; ++mt)
#pragma unroll
            for (int u = 0; u < 4; ++u) c2[mt][u] = (f32x4){0.f, 0.f, 0.f, 0.f};
#pragma unroll
        for (int jtL = 0; jtL < 4; ++jtL) {
            int jt = h * 4 + jtL;
            uint4 Bf[4];
#pragma unroll
            for (int is = 0; is < 4; ++is) Bf[is] = wrw[(jt * 4 + is) * 64 + l];
#pragma unroll
            for (int mt = 0; mt < 4; ++mt)
#pragma unroll
                for (int is = 0; is < 4; ++is)
                    c2[mt][jtL] = __builtin_amdgcn_mfma_f32_16x16x32_bf16(
                        __builtin_bit_cast(bf16x8, A2[mt][is]),
                        __builtin_bit_cast(bf16x8, Bf[is]), c2[mt][jtL], 0, 0, 0);
        }
        // scatter dh1 (bf16) into [m][j] row-major (swizzled)
#pragma unroll
        for (int jtL = 0; jtL < 4; ++jtL) {
            int jt = h * 4 + jtL;
            int jb = (jt * 16 + low) * 2;
#pragma unroll
            for (int mt = 0; mt < 4; ++mt)
#pragma unroll
                for (int r = 0; r < 4; ++r) {
                    int q = lk * 4 + r;
                    int ml = mt * 16 + q;
                    int byte = wb + ml * 256 + jb;
                    byte ^= (q & 7) << 4;
                    sBuf[byte >> 1] = bf16rne(c2[mt][jtL][r]);
                }
        }
    }

    // ---- per-thread backward: dp = 30*cos(30*pre1)*dh1 ; dh = dp @ W0^T ----
    float dh[11];
#pragma unroll
    for (int k = 0; k < 11; ++k) dh[k] = 0.f;

#pragma unroll
    for (int o = 0; o < 16; ++o) {
        int byte = wb + mloc * 256 + o * 16;
        byte ^= (mloc & 7) << 4;
        uint4 dq = *(const uint4*)&sBuf[byte >> 1];
        float dj[8];
        dj[0] = lo2(dq.x); dj[1] = hi2(dq.x);
        dj[2] = lo2(dq.y); dj[3] = hi2(dq.y);
        dj[4] = lo2(dq.z); dj[5] = hi2(dq.z);
        dj[6] = lo2(dq.w); dj[7] = hi2(dq.w);
#pragma unroll
        for (int jj = 0; jj < 8; ++jj) {
            int j = o * 8 + jj;
            const float4* wr = (const float4*)&sW0t[j * 12];
            float4 wa = wr[0], wbq = wr[1], wc = wr[2];
            float a = sB0[j]
                + xe[0] * wa.x + xe[1] * wa.y + xe[2] * wa.z + xe[3] * wa.w
                + xe[4] * wbq.x + xe[5] * wbq.y + xe[6] * wbq.z + xe[7] * wbq.w
                + px * wc.x + py * wc.y + pz * wc.z;
            float cc = __cosf(W0F * a);
            float dp = W0F * cc * dj[jj];
            dh[0] += dp * wa.x;  dh[1] += dp * wa.y;  dh[2] += dp * wa.z;  dh[3] += dp * wa.w;
            dh[4] += dp * wbq.x; dh[5] += dp * wbq.y; dh[6] += dp * wbq.z; dh[7] += dp * wbq.w;
            dh[8] += dp * wc.x;  dh[9] += dp * wc.y;  dh[10] += dp * wc.z;
        }
    }

    float gx = dh[8], gy = dh[9], gz = dh[10];
#pragma unroll
    for (int k = 0; k < 8; k += 2) {
        unsigned ex = jxp[k >> 1], ey = jyp[k >> 1], ez = jzp[k >> 1];
        gx += lo2(ex) * dh[k] + hi2(ex) * dh[k + 1];
        gy += lo2(ey) * dh[k] + hi2(ey) * dh[k + 1];
        gz += lo2(ez) * dh[k] + hi2(ez) * dh[k + 1];
    }

    out[N + 3 * n + 0] = gx;
    out[N + 3 * n + 1] = gy;
    out[N + 3 * n + 2] = gz;
}

extern "C" void kernel_launch(void* const* d_in, const int* in_sizes, int n_in,
                              void* d_out, int out_size, void* d_ws, size_t ws_size,
                              hipStream_t stream) {
    const float* pos  = (const float*)d_in[0];
    const float* grid = (const float*)d_in[1];
    const float* W0   = (const float*)d_in[2];
    const float* b0   = (const float*)d_in[3];
    const float* W1   = (const float*)d_in[4];
    const float* b1   = (const float*)d_in[5];
    const float* Wo   = (const float*)d_in[6];
    const float* bo   = (const float*)d_in[7];
    float* out = (float*)d_out;
    unsigned short* ws = (unsigned short*)d_ws;
    const int N = in_sizes[0] / 3;

    prep_kernel<<<64, 256, 0, stream>>>(W1, ws);
    nsdf_main<<<N / 256, 256, 0, stream>>>(pos, grid, W0, b0, b1, Wo, bo, ws, out, N);
}

// Round 5
// 670.546 us; speedup vs baseline: 12.9598x; 1.6045x over previous
//
#include <hip/hip_runtime.h>

#define RES 128
#define HID 128
#define W0F 30.0f
#define SCALE 63.5f

typedef __bf16 bf16x8 __attribute__((ext_vector_type(8)));
typedef float f32x4 __attribute__((ext_vector_type(4)));

__device__ __forceinline__ unsigned short bf16rne(float x) {
    unsigned u = __float_as_uint(x);
    u = (u + 0x7fffu + ((u >> 16) & 1u)) >> 16;
    return (unsigned short)u;
}
__device__ __forceinline__ unsigned pk2f(float a, float b) {
    return (unsigned)bf16rne(a) | ((unsigned)bf16rne(b) << 16);
}
__device__ __forceinline__ float lo2(unsigned p) { return __uint_as_float(p << 16); }
__device__ __forceinline__ float hi2(unsigned p) { return __uint_as_float(p & 0xffff0000u); }

// ---- prep: W1 fp32 -> two fragment-ordered bf16 copies in d_ws ----
// layout: ws[(tile*64 + lane)*8 + e]; tile = hi16*4 + ks
//   copy0 (colT, for GEMM1 B: k=j): value = W1[ks*32+(lane>>4)*8+e][hi16*16+(lane&15)]
//   copy1 (row,  for GEMM2 B: k=i): value = W1[hi16*16+(lane&15)][ks*32+(lane>>4)*8+e]
__global__ void prep_kernel(const float* __restrict__ W1, unsigned short* __restrict__ ws) {
    int t = blockIdx.x * blockDim.x + threadIdx.x;   // 0..16383
    int tile = t >> 9;
    int lane = (t >> 3) & 63;
    int e = t & 7;
    int hi16 = tile >> 2;
    int ks = tile & 3;
    int koff = ks * 32 + (lane >> 4) * 8 + e;
    int noff = hi16 * 16 + (lane & 15);
    ws[t] = bf16rne(W1[koff * HID + noff]);
    ws[16384 + t] = bf16rne(W1[noff * HID + koff]);
}

__global__ __launch_bounds__(256, 2)
void nsdf_main(const float* __restrict__ pos, const float* __restrict__ grid,
               const float* __restrict__ W0, const float* __restrict__ b0,
               const float* __restrict__ b1, const float* __restrict__ Wo,
               const float* __restrict__ bo, const unsigned short* __restrict__ wfrag,
               float* __restrict__ out, int N)
{
    __shared__ unsigned short sBuf[4 * 8192];   // 64 KB: one 16 KB wave-private region each
    __shared__ float sW0t[HID * 12];            // [j][k], k padded to 12
    __shared__ float sB0[HID], sB1v[HID], sWov[HID];
    __shared__ float sBo;

    const int tid = threadIdx.x;
    const int l = tid & 63;
    const int wid = tid >> 6;
    const int low = l & 15;
    const int lk = l >> 4;
    const int wb = wid * 16384;   // byte base of this wave's region
    const int mloc = l;           // local point index within wave

    // ---- stage small weights (overlaps with encode's global gather) ----
    if (tid < HID) {
        sB0[tid] = b0[tid];
        sB1v[tid] = b1[tid];
        sWov[tid] = Wo[tid];
#pragma unroll
        for (int k = 0; k < 11; ++k) sW0t[tid * 12 + k] = W0[k * HID + tid];
        sW0t[tid * 12 + 11] = 0.f;
    }
    if (tid == 0) sBo = bo[0];

    const int n = blockIdx.x * 256 + tid;
    const float px = pos[3 * n], py = pos[3 * n + 1], pz = pos[3 * n + 2];

    // ---- encode: smoothstep trilinear + Jacobian ----
    const float upper = 126.999992f;
    float fx = fminf(fmaxf((px + 1.f) * 0.5f * (RES - 1), 0.f), upper);
    float fy = fminf(fmaxf((py + 1.f) * 0.5f * (RES - 1), 0.f), upper);
    float fz = fminf(fmaxf((pz + 1.f) * 0.5f * (RES - 1), 0.f), upper);
    int ix0 = (int)fx, iy0 = (int)fy, iz0 = (int)fz;
    float tx = fx - (float)ix0, ty = fy - (float)iy0, tz = fz - (float)iz0;
    float wx = tx * tx * (3.f - 2.f * tx);
    float wy = ty * ty * (3.f - 2.f * ty);
    float wz = tz * tz * (3.f - 2.f * tz);
    float dwx = 6.f * tx * (1.f - tx) * SCALE;
    float dwy = 6.f * ty * (1.f - ty) * SCALE;
    float dwz = 6.f * tz * (1.f - tz) * SCALE;

    const float4* g4 = (const float4*)grid;
    int b000 = ((ix0 * RES + iy0) * RES + iz0) * 2;
    int b010 = ((ix0 * RES + (iy0 + 1)) * RES + iz0) * 2;
    int b100 = (((ix0 + 1) * RES + iy0) * RES + iz0) * 2;
    int b110 = (((ix0 + 1) * RES + (iy0 + 1)) * RES + iz0) * 2;

    float c000[8], c001[8], c010[8], c011[8], c100[8], c101[8], c110[8], c111[8];
    *(float4*)&c000[0] = g4[b000];     *(float4*)&c000[4] = g4[b000 + 1];
    *(float4*)&c001[0] = g4[b000 + 2]; *(float4*)&c001[4] = g4[b000 + 3];
    *(float4*)&c010[0] = g4[b010];     *(float4*)&c010[4] = g4[b010 + 1];
    *(float4*)&c011[0] = g4[b010 + 2]; *(float4*)&c011[4] = g4[b010 + 3];
    *(float4*)&c100[0] = g4[b100];     *(float4*)&c100[4] = g4[b100 + 1];
    *(float4*)&c101[0] = g4[b100 + 2]; *(float4*)&c101[4] = g4[b100 + 3];
    *(float4*)&c110[0] = g4[b110];     *(float4*)&c110[4] = g4[b110 + 1];
    *(float4*)&c111[0] = g4[b110 + 2]; *(float4*)&c111[4] = g4[b110 + 3];

    unsigned embp[4], jxp[4], jyp[4], jzp[4];   // packed bf16: emb + Jacobian
#pragma unroll
    for (int k = 0; k < 8; k += 2) {
        float em[2], ex[2], ey[2], ez[2];
#pragma unroll
        for (int qq = 0; qq < 2; ++qq) {
            int kk = k + qq;
            float a000 = c000[kk], a001 = c001[kk], a010 = c010[kk], a011 = c011[kk];
            float a100 = c100[kk], a101 = c101[kk], a110 = c110[kk], a111 = c111[kk];
            float dX00 = a100 - a000, dX10 = a110 - a010;
            float dX01 = a101 - a001, dX11 = a111 - a011;
            float c00 = a000 + dX00 * wx;
            float c10 = a010 + dX10 * wx;
            float c01 = a001 + dX01 * wx;
            float c11 = a011 + dX11 * wx;
            float cy0 = c00 + (c10 - c00) * wy;
            float cy1 = c01 + (c11 - c01) * wy;
            em[qq] = cy0 + (cy1 - cy0) * wz;
            ez[qq] = (cy1 - cy0) * dwz;
            float dy0 = c10 - c00, dy1 = c11 - c01;
            ey[qq] = (dy0 + (dy1 - dy0) * wz) * dwy;
            float dx0 = dX00 + (dX10 - dX00) * wy;
            float dx1 = dX01 + (dX11 - dX01) * wy;
            ex[qq] = (dx0 + (dx1 - dx0) * wz) * dwx;
        }
        embp[k >> 1] = pk2f(em[0], em[1]);
        jxp[k >> 1] = pk2f(ex[0], ex[1]);
        jyp[k >> 1] = pk2f(ey[0], ey[1]);
        jzp[k >> 1] = pk2f(ez[0], ez[1]);
    }

    float xe[8];
#pragma unroll
    for (int k = 0; k < 4; ++k) { xe[2 * k] = lo2(embp[k]); xe[2 * k + 1] = hi2(embp[k]); }

    __syncthreads();

    // ---- layer 1 fwd (per-thread): h1 = sin(30*pre1) -> A1-frag-ordered LDS ----
    const int q15 = mloc & 15, mtOwn = mloc >> 4;
#pragma unroll
    for (int o = 0; o < 16; ++o) {
        float sv[8];
#pragma unroll
        for (int jj = 0; jj < 8; ++jj) {
            int j = o * 8 + jj;
            const float4* wr = (const float4*)&sW0t[j * 12];
            float4 wa = wr[0], wbq = wr[1], wc = wr[2];
            float a = sB0[j]
                + xe[0] * wa.x + xe[1] * wa.y + xe[2] * wa.z + xe[3] * wa.w
                + xe[4] * wbq.x + xe[5] * wbq.y + xe[6] * wbq.z + xe[7] * wbq.w
                + px * wc.x + py * wc.y + pz * wc.z;
            sv[jj] = __sinf(W0F * a);
        }
        uint4 w4;
        w4.x = pk2f(sv[0], sv[1]); w4.y = pk2f(sv[2], sv[3]);
        w4.z = pk2f(sv[4], sv[5]); w4.w = pk2f(sv[6], sv[7]);
        int byte = wb + (o >> 2) * 4096 + q15 * 256 + mtOwn * 64 + (o & 3) * 16;
        byte ^= (mloc & 7) << 4;
        *(uint4*)&sBuf[byte >> 1] = w4;
    }

    // ---- GEMM1: pre2 = h1 @ W1 (M=64/wave, N=128, K=128) ----
    uint4 A1[4][4];
#pragma unroll
    for (int mt = 0; mt < 4; ++mt)
#pragma unroll
        for (int js = 0; js < 4; ++js) {
            int byte = wb + js * 4096 + low * 256 + mt * 64 + lk * 16;
            byte ^= (low & 7) << 4;
            A1[mt][js] = *(const uint4*)&sBuf[byte >> 1];
        }

    const uint4* wct = (const uint4*)wfrag;             // colT frags (GEMM1 B)
    const uint4* wrw = (const uint4*)(wfrag + 16384);   // row frags (GEMM2 B)

    float sdfp[4][4];
#pragma unroll
    for (int a = 0; a < 4; ++a)
#pragma unroll
        for (int b = 0; b < 4; ++b) sdfp[a][b] = 0.f;

#pragma unroll
    for (int h = 0; h < 2; ++h) {
        f32x4 c1[4][4];
#pragma unroll
        for (int mt = 0; mt < 4; ++mt)
#pragma unroll
            for (int u = 0; u < 4; ++u) c1[mt][u] = (f32x4){0.f, 0.f, 0.f, 0.f};
#pragma unroll
        for (int ntL = 0; ntL < 4; ++ntL) {
            int nt = h * 4 + ntL;
            uint4 Bf[4];
#pragma unroll
            for (int js = 0; js < 4; ++js) Bf[js] = wct[(nt * 4 + js) * 64 + l];
#pragma unroll
            for (int mt = 0; mt < 4; ++mt)
#pragma unroll
                for (int js = 0; js < 4; ++js)
                    c1[mt][ntL] = __builtin_amdgcn_mfma_f32_16x16x32_bf16(
                        __builtin_bit_cast(bf16x8, A1[mt][js]),
                        __builtin_bit_cast(bf16x8, Bf[js]), c1[mt][ntL], 0, 0, 0);
        }
        // v-phase: sincos on C1, accumulate sdf, scatter v (bf16) into A2-frag order
#pragma unroll
        for (int ntL = 0; ntL < 4; ++ntL) {
            int nt = h * 4 + ntL;
            int i = nt * 16 + low;
            float b1e = sB1v[i], woe = sWov[i];
            int istep = nt >> 1;
            int i32 = (nt & 1) * 16 + low;
            int ibyte = (i32 >> 3) * 16 + (i32 & 7) * 2;
#pragma unroll
            for (int mt = 0; mt < 4; ++mt)
#pragma unroll
                for (int r = 0; r < 4; ++r) {
                    float pre = c1[mt][ntL][r] + b1e;
                    float s, c;
                    __sincosf(W0F * pre, &s, &c);
                    sdfp[mt][r] += woe * s;
                    float v = W0F * c * woe;
                    int q = lk * 4 + r;
                    int byte = wb + istep * 4096 + q * 256 + mt * 64 + ibyte;
                    byte ^= (q & 7) << 4;
                    sBuf[byte >> 1] = bf16rne(v);
                }
        }
    }

    // ---- sdf reduce (over 16 lanes sharing i-range) + store ----
    {
        int blkBase = blockIdx.x * 256 + wid * 64;
        float boV = sBo;
#pragma unroll
        for (int mt = 0; mt < 4; ++mt)
#pragma unroll
            for (int r = 0; r < 4; ++r) {
                float sv = sdfp[mt][r];
                sv += __shfl_xor(sv, 1);
                sv += __shfl_xor(sv, 2);
                sv += __shfl_xor(sv, 4);
                sv += __shfl_xor(sv, 8);
                if (low == 0) out[blkBase + mt * 16 + lk * 4 + r] = sv + boV;
            }
    }

    // ---- GEMM2: dh1 = v @ W1^T ----
    uint4 A2[4][4];
#pragma unroll
    for (int mt = 0; mt < 4; ++mt)
#pragma unroll
        for (int is = 0; is < 4; ++is) {
            int byte = wb + is * 4096 + low * 256 + mt * 64 + lk * 16;
            byte ^= (low & 7) << 4;
            A2[mt][is] = *(const uint4*)&sBuf[byte >> 1];
        }

#pragma unroll
    for (int h = 0; h < 2; ++h) {
        f32x4 c2[4][4];
#pragma unroll
        for (int mt = 0; mt < 4; ++mt)
#pragma unroll
            for (int u = 0; u < 4; ++u) c2[mt][u] = (f32x4){0.f, 0.f, 0.f, 0.f};
#pragma unroll
        for (int jtL = 0; jtL < 4; ++jtL) {
            int jt = h * 4 + jtL;
            uint4 Bf[4];
#pragma unroll
            for (int is = 0; is < 4; ++is) Bf[is] = wrw[(jt * 4 + is) * 64 + l];
#pragma unroll
            for (int mt = 0; mt < 4; ++mt)
#pragma unroll
                for (int is = 0; is < 4; ++is)
                    c2[mt][jtL] = __builtin_amdgcn_mfma_f32_16x16x32_bf16(
                        __builtin_bit_cast(bf16x8, A2[mt][is]),
                        __builtin_bit_cast(bf16x8, Bf[is]), c2[mt][jtL], 0, 0, 0);
        }
        // scatter dh1 (bf16) into [m][j] row-major (swizzled)
#pragma unroll
        for (int jtL = 0; jtL < 4; ++jtL) {
            int jt = h * 4 + jtL;
            int jb = (jt * 16 + low) * 2;
#pragma unroll
            for (int mt = 0; mt < 4; ++mt)
#pragma unroll
                for (int r = 0; r < 4; ++r) {
                    int q = lk * 4 + r;
                    int ml = mt * 16 + q;
                    int byte = wb + ml * 256 + jb;
                    byte ^= (q & 7) << 4;
                    sBuf[byte >> 1] = bf16rne(c2[mt][jtL][r]);
                }
        }
    }

    // ---- per-thread backward: dp = 30*cos(30*pre1)*dh1 ; dh = dp @ W0^T ----
    float dh[11];
#pragma unroll
    for (int k = 0; k < 11; ++k) dh[k] = 0.f;

#pragma unroll
    for (int o = 0; o < 16; ++o) {
        int byte = wb + mloc * 256 + o * 16;
        byte ^= (mloc & 7) << 4;
        uint4 dq = *(const uint4*)&sBuf[byte >> 1];
        float dj[8];
        dj[0] = lo2(dq.x); dj[1] = hi2(dq.x);
        dj[2] = lo2(dq.y); dj[3] = hi2(dq.y);
        dj[4] = lo2(dq.z); dj[5] = hi2(dq.z);
        dj[6] = lo2(dq.w); dj[7] = hi2(dq.w);
#pragma unroll
        for (int jj = 0; jj < 8; ++jj) {
            int j = o * 8 + jj;
            const float4* wr = (const float4*)&sW0t[j * 12];
            float4 wa = wr[0], wbq = wr[1], wc = wr[2];
            float a = sB0[j]
                + xe[0] * wa.x + xe[1] * wa.y + xe[2] * wa.z + xe[3] * wa.w
                + xe[4] * wbq.x + xe[5] * wbq.y + xe[6] * wbq.z + xe[7] * wbq.w
                + px * wc.x + py * wc.y + pz * wc.z;
            float cc = __cosf(W0F * a);
            float dp = W0F * cc * dj[jj];
            dh[0] += dp * wa.x;  dh[1] += dp * wa.y;  dh[2] += dp * wa.z;  dh[3] += dp * wa.w;
            dh[4] += dp * wbq.x; dh[5] += dp * wbq.y; dh[6] += dp * wbq.z; dh[7] += dp * wbq.w;
            dh[8] += dp * wc.x;  dh[9] += dp * wc.y;  dh[10] += dp * wc.z;
        }
    }

    float gx = dh[8], gy = dh[9], gz = dh[10];
#pragma unroll
    for (int k = 0; k < 8; k += 2) {
        unsigned ex = jxp[k >> 1], ey = jyp[k >> 1], ez = jzp[k >> 1];
        gx += lo2(ex) * dh[k] + hi2(ex) * dh[k + 1];
        gy += lo2(ey) * dh[k] + hi2(ey) * dh[k + 1];
        gz += lo2(ez) * dh[k] + hi2(ez) * dh[k + 1];
    }

    out[N + 3 * n + 0] = gx;
    out[N + 3 * n + 1] = gy;
    out[N + 3 * n + 2] = gz;
}

extern "C" void kernel_launch(void* const* d_in, const int* in_sizes, int n_in,
                              void* d_out, int out_size, void* d_ws, size_t ws_size,
                              hipStream_t stream) {
    const float* pos  = (const float*)d_in[0];
    const float* grid = (const float*)d_in[1];
    const float* W0   = (const float*)d_in[2];
    const float* b0   = (const float*)d_in[3];
    const float* W1   = (const float*)d_in[4];
    const float* b1   = (const float*)d_in[5];
    const float* Wo   = (const float*)d_in[6];
    const float* bo   = (const float*)d_in[7];
    float* out = (float*)d_out;
    unsigned short* ws = (unsigned short*)d_ws;
    const int N = in_sizes[0] / 3;

    prep_kernel<<<64, 256, 0, stream>>>(W1, ws);
    nsdf_main<<<N / 256, 256, 0, stream>>>(pos, grid, W0, b0, b1, Wo, bo, ws, out, N);
}

// Round 6
// 563.001 us; speedup vs baseline: 15.4354x; 1.1910x over previous
//
#include <hip/hip_runtime.h>

#define RES 128
#define HID 128
#define W0F 30.0f
#define SCALE 63.5f

typedef __bf16 bf16x8 __attribute__((ext_vector_type(8)));
typedef float f32x4 __attribute__((ext_vector_type(4)));

__device__ __forceinline__ unsigned short bf16rne(float x) {
    unsigned u = __float_as_uint(x);
    u = (u + 0x7fffu + ((u >> 16) & 1u)) >> 16;
    return (unsigned short)u;
}
__device__ __forceinline__ unsigned pk2f(float a, float b) {
    return (unsigned)bf16rne(a) | ((unsigned)bf16rne(b) << 16);
}
__device__ __forceinline__ float lo2(unsigned p) { return __uint_as_float(p << 16); }
__device__ __forceinline__ float hi2(unsigned p) { return __uint_as_float(p & 0xffff0000u); }

// ---- prep: W1 fp32 -> two fragment-ordered bf16 copies in d_ws ----
// layout: ws[(tile*64 + lane)*8 + e]; tile = hi16*4 + ks
//   copy0 (colT, for GEMM1 B: k=j): value = W1[ks*32+(lane>>4)*8+e][hi16*16+(lane&15)]
//   copy1 (row,  for GEMM2 B: k=i): value = W1[hi16*16+(lane&15)][ks*32+(lane>>4)*8+e]
__global__ void prep_kernel(const float* __restrict__ W1, unsigned short* __restrict__ ws) {
    int t = blockIdx.x * blockDim.x + threadIdx.x;   // 0..16383
    int tile = t >> 9;
    int lane = (t >> 3) & 63;
    int e = t & 7;
    int hi16 = tile >> 2;
    int ks = tile & 3;
    int koff = ks * 32 + (lane >> 4) * 8 + e;
    int noff = hi16 * 16 + (lane & 15);
    ws[t] = bf16rne(W1[koff * HID + noff]);
    ws[16384 + t] = bf16rne(W1[noff * HID + koff]);
}

__global__ __launch_bounds__(256, 2)
void nsdf_main(const float* __restrict__ pos, const float* __restrict__ grid,
               const float* __restrict__ W0, const float* __restrict__ b0,
               const float* __restrict__ b1, const float* __restrict__ Wo,
               const float* __restrict__ bo, const unsigned short* __restrict__ wfrag,
               float* __restrict__ out, int N)
{
    __shared__ unsigned short sBuf[4 * 8192];   // 64 KB: one 16 KB wave-private region each
    __shared__ float sW0t[HID * 12];            // [j][k], k padded to 12
    __shared__ float sB0[HID], sB1v[HID], sWov[HID];
    __shared__ float sBo;

    const int tid = threadIdx.x;
    const int l = tid & 63;
    const int wid = tid >> 6;
    const int low = l & 15;
    const int lk = l >> 4;
    const int wb = wid * 16384;   // byte base of this wave's region
    const int mloc = l;           // local point index within wave

    // ---- stage small weights (overlaps with encode's global gather) ----
    if (tid < HID) {
        sB0[tid] = b0[tid];
        sB1v[tid] = b1[tid];
        sWov[tid] = Wo[tid];
#pragma unroll
        for (int k = 0; k < 11; ++k) sW0t[tid * 12 + k] = W0[k * HID + tid];
        sW0t[tid * 12 + 11] = 0.f;
    }
    if (tid == 0) sBo = bo[0];

    const int n = blockIdx.x * 256 + tid;
    const float px = pos[3 * n], py = pos[3 * n + 1], pz = pos[3 * n + 2];

    // ---- encode: smoothstep trilinear + Jacobian ----
    const float upper = 126.999992f;
    float fx = fminf(fmaxf((px + 1.f) * 0.5f * (RES - 1), 0.f), upper);
    float fy = fminf(fmaxf((py + 1.f) * 0.5f * (RES - 1), 0.f), upper);
    float fz = fminf(fmaxf((pz + 1.f) * 0.5f * (RES - 1), 0.f), upper);
    int ix0 = (int)fx, iy0 = (int)fy, iz0 = (int)fz;
    float tx = fx - (float)ix0, ty = fy - (float)iy0, tz = fz - (float)iz0;
    float wx = tx * tx * (3.f - 2.f * tx);
    float wy = ty * ty * (3.f - 2.f * ty);
    float wz = tz * tz * (3.f - 2.f * tz);
    float dwx = 6.f * tx * (1.f - tx) * SCALE;
    float dwy = 6.f * ty * (1.f - ty) * SCALE;
    float dwz = 6.f * tz * (1.f - tz) * SCALE;

    const float4* g4 = (const float4*)grid;
    int b000 = ((ix0 * RES + iy0) * RES + iz0) * 2;
    int b010 = ((ix0 * RES + (iy0 + 1)) * RES + iz0) * 2;
    int b100 = (((ix0 + 1) * RES + iy0) * RES + iz0) * 2;
    int b110 = (((ix0 + 1) * RES + (iy0 + 1)) * RES + iz0) * 2;

    float c000[8], c001[8], c010[8], c011[8], c100[8], c101[8], c110[8], c111[8];
    *(float4*)&c000[0] = g4[b000];     *(float4*)&c000[4] = g4[b000 + 1];
    *(float4*)&c001[0] = g4[b000 + 2]; *(float4*)&c001[4] = g4[b000 + 3];
    *(float4*)&c010[0] = g4[b010];     *(float4*)&c010[4] = g4[b010 + 1];
    *(float4*)&c011[0] = g4[b010 + 2]; *(float4*)&c011[4] = g4[b010 + 3];
    *(float4*)&c100[0] = g4[b100];     *(float4*)&c100[4] = g4[b100 + 1];
    *(float4*)&c101[0] = g4[b100 + 2]; *(float4*)&c101[4] = g4[b100 + 3];
    *(float4*)&c110[0] = g4[b110];     *(float4*)&c110[4] = g4[b110 + 1];
    *(float4*)&c111[0] = g4[b110 + 2]; *(float4*)&c111[4] = g4[b110 + 3];

    unsigned embp[4], jxp[4], jyp[4], jzp[4];   // packed bf16: emb + Jacobian
#pragma unroll
    for (int k = 0; k < 8; k += 2) {
        float em[2], ex[2], ey[2], ez[2];
#pragma unroll
        for (int qq = 0; qq < 2; ++qq) {
            int kk = k + qq;
            float a000 = c000[kk], a001 = c001[kk], a010 = c010[kk], a011 = c011[kk];
            float a100 = c100[kk], a101 = c101[kk], a110 = c110[kk], a111 = c111[kk];
            float dX00 = a100 - a000, dX10 = a110 - a010;
            float dX01 = a101 - a001, dX11 = a111 - a011;
            float c00 = a000 + dX00 * wx;
            float c10 = a010 + dX10 * wx;
            float c01 = a001 + dX01 * wx;
            float c11 = a011 + dX11 * wx;
            float cy0 = c00 + (c10 - c00) * wy;
            float cy1 = c01 + (c11 - c01) * wy;
            em[qq] = cy0 + (cy1 - cy0) * wz;
            ez[qq] = (cy1 - cy0) * dwz;
            float dy0 = c10 - c00, dy1 = c11 - c01;
            ey[qq] = (dy0 + (dy1 - dy0) * wz) * dwy;
            float dx0 = dX00 + (dX10 - dX00) * wy;
            float dx1 = dX01 + (dX11 - dX01) * wy;
            ex[qq] = (dx0 + (dx1 - dx0) * wz) * dwx;
        }
        embp[k >> 1] = pk2f(em[0], em[1]);
        jxp[k >> 1] = pk2f(ex[0], ex[1]);
        jyp[k >> 1] = pk2f(ey[0], ey[1]);
        jzp[k >> 1] = pk2f(ez[0], ez[1]);
    }

    float xe[8];
#pragma unroll
    for (int k = 0; k < 4; ++k) { xe[2 * k] = lo2(embp[k]); xe[2 * k + 1] = hi2(embp[k]); }

    __syncthreads();

    // ---- layer 1 fwd (per-thread): h1 = sin(30*pre1) -> A1-frag-ordered LDS ----
    const int q15 = mloc & 15, mtOwn = mloc >> 4;
#pragma unroll
    for (int o = 0; o < 16; ++o) {
        float sv[8];
#pragma unroll
        for (int jj = 0; jj < 8; ++jj) {
            int j = o * 8 + jj;
            const float4* wr = (const float4*)&sW0t[j * 12];
            float4 wa = wr[0], wbq = wr[1], wc = wr[2];
            float a = sB0[j]
                + xe[0] * wa.x + xe[1] * wa.y + xe[2] * wa.z + xe[3] * wa.w
                + xe[4] * wbq.x + xe[5] * wbq.y + xe[6] * wbq.z + xe[7] * wbq.w
                + px * wc.x + py * wc.y + pz * wc.z;
            sv[jj] = __sinf(W0F * a);
        }
        uint4 w4;
        w4.x = pk2f(sv[0], sv[1]); w4.y = pk2f(sv[2], sv[3]);
        w4.z = pk2f(sv[4], sv[5]); w4.w = pk2f(sv[6], sv[7]);
        int byte = wb + (o >> 2) * 4096 + q15 * 256 + mtOwn * 64 + (o & 3) * 16;
        byte ^= (mloc & 7) << 4;
        *(uint4*)&sBuf[byte >> 1] = w4;
    }

    // ---- GEMM1: pre2 = h1 @ W1, streamed one 16-col tile at a time ----
    uint4 A1[4][4];
#pragma unroll
    for (int mt = 0; mt < 4; ++mt)
#pragma unroll
        for (int js = 0; js < 4; ++js) {
            int byte = wb + js * 4096 + low * 256 + mt * 64 + lk * 16;
            byte ^= (low & 7) << 4;
            A1[mt][js] = *(const uint4*)&sBuf[byte >> 1];
        }

    const uint4* wct = (const uint4*)wfrag;             // colT frags (GEMM1 B)
    const uint4* wrw = (const uint4*)(wfrag + 16384);   // row frags (GEMM2 B)

    float sdfp[4][4];
#pragma unroll
    for (int a = 0; a < 4; ++a)
#pragma unroll
        for (int b = 0; b < 4; ++b) sdfp[a][b] = 0.f;

#pragma unroll 1
    for (int nt = 0; nt < 8; ++nt) {
        uint4 Bf[4];
#pragma unroll
        for (int js = 0; js < 4; ++js) Bf[js] = wct[(nt * 4 + js) * 64 + l];
        f32x4 c1[4];
#pragma unroll
        for (int mt = 0; mt < 4; ++mt) c1[mt] = (f32x4){0.f, 0.f, 0.f, 0.f};
#pragma unroll
        for (int mt = 0; mt < 4; ++mt)
#pragma unroll
            for (int js = 0; js < 4; ++js)
                c1[mt] = __builtin_amdgcn_mfma_f32_16x16x32_bf16(
                    __builtin_bit_cast(bf16x8, A1[mt][js]),
                    __builtin_bit_cast(bf16x8, Bf[js]), c1[mt], 0, 0, 0);
        // v-phase for this tile: sincos, sdf accum, scatter v into A2-frag order
        int i = nt * 16 + low;
        float b1e = sB1v[i], woe = sWov[i];
        int istep = nt >> 1;
        int i32 = (nt & 1) * 16 + low;
        int ibyte = (i32 >> 3) * 16 + (i32 & 7) * 2;
#pragma unroll
        for (int mt = 0; mt < 4; ++mt)
#pragma unroll
            for (int r = 0; r < 4; ++r) {
                float pre = c1[mt][r] + b1e;
                float s, c;
                __sincosf(W0F * pre, &s, &c);
                sdfp[mt][r] += woe * s;
                float v = W0F * c * woe;
                int q = lk * 4 + r;
                int byte = wb + istep * 4096 + q * 256 + mt * 64 + ibyte;
                byte ^= (q & 7) << 4;
                sBuf[byte >> 1] = bf16rne(v);
            }
    }

    // ---- sdf reduce (over 16 lanes sharing i-range) + store ----
    {
        int blkBase = blockIdx.x * 256 + wid * 64;
        float boV = sBo;
#pragma unroll
        for (int mt = 0; mt < 4; ++mt)
#pragma unroll
            for (int r = 0; r < 4; ++r) {
                float sv = sdfp[mt][r];
                sv += __shfl_xor(sv, 1);
                sv += __shfl_xor(sv, 2);
                sv += __shfl_xor(sv, 4);
                sv += __shfl_xor(sv, 8);
                if (low == 0) out[blkBase + mt * 16 + lk * 4 + r] = sv + boV;
            }
    }

    // ---- GEMM2: dh1 = v @ W1^T, streamed one 16-col tile at a time ----
    uint4 A2[4][4];
#pragma unroll
    for (int mt = 0; mt < 4; ++mt)
#pragma unroll
        for (int is = 0; is < 4; ++is) {
            int byte = wb + is * 4096 + low * 256 + mt * 64 + lk * 16;
            byte ^= (low & 7) << 4;
            A2[mt][is] = *(const uint4*)&sBuf[byte >> 1];
        }

#pragma unroll 1
    for (int jt = 0; jt < 8; ++jt) {
        uint4 Bf[4];
#pragma unroll
        for (int is = 0; is < 4; ++is) Bf[is] = wrw[(jt * 4 + is) * 64 + l];
        f32x4 c2[4];
#pragma unroll
        for (int mt = 0; mt < 4; ++mt) c2[mt] = (f32x4){0.f, 0.f, 0.f, 0.f};
#pragma unroll
        for (int mt = 0; mt < 4; ++mt)
#pragma unroll
            for (int is = 0; is < 4; ++is)
                c2[mt] = __builtin_amdgcn_mfma_f32_16x16x32_bf16(
                    __builtin_bit_cast(bf16x8, A2[mt][is]),
                    __builtin_bit_cast(bf16x8, Bf[is]), c2[mt], 0, 0, 0);
        // scatter dh1 (bf16) into [m][j] row-major (swizzled)
        int jb = (jt * 16 + low) * 2;
#pragma unroll
        for (int mt = 0; mt < 4; ++mt)
#pragma unroll
            for (int r = 0; r < 4; ++r) {
                int q = lk * 4 + r;
                int ml = mt * 16 + q;
                int byte = wb + ml * 256 + jb;
                byte ^= (q & 7) << 4;
                sBuf[byte >> 1] = bf16rne(c2[mt][r]);
            }
    }

    // ---- per-thread backward: dp = 30*cos(30*pre1)*dh1 ; dh = dp @ W0^T ----
    float dh[11];
#pragma unroll
    for (int k = 0; k < 11; ++k) dh[k] = 0.f;

#pragma unroll
    for (int o = 0; o < 16; ++o) {
        int byte = wb + mloc * 256 + o * 16;
        byte ^= (mloc & 7) << 4;
        uint4 dq = *(const uint4*)&sBuf[byte >> 1];
        float dj[8];
        dj[0] = lo2(dq.x); dj[1] = hi2(dq.x);
        dj[2] = lo2(dq.y); dj[3] = hi2(dq.y);
        dj[4] = lo2(dq.z); dj[5] = hi2(dq.z);
        dj[6] = lo2(dq.w); dj[7] = hi2(dq.w);
#pragma unroll
        for (int jj = 0; jj < 8; ++jj) {
            int j = o * 8 + jj;
            const float4* wr = (const float4*)&sW0t[j * 12];
            float4 wa = wr[0], wbq = wr[1], wc = wr[2];
            float a = sB0[j]
                + xe[0] * wa.x + xe[1] * wa.y + xe[2] * wa.z + xe[3] * wa.w
                + xe[4] * wbq.x + xe[5] * wbq.y + xe[6] * wbq.z + xe[7] * wbq.w
                + px * wc.x + py * wc.y + pz * wc.z;
            float cc = __cosf(W0F * a);
            float dp = W0F * cc * dj[jj];
            dh[0] += dp * wa.x;  dh[1] += dp * wa.y;  dh[2] += dp * wa.z;  dh[3] += dp * wa.w;
            dh[4] += dp * wbq.x; dh[5] += dp * wbq.y; dh[6] += dp * wbq.z; dh[7] += dp * wbq.w;
            dh[8] += dp * wc.x;  dh[9] += dp * wc.y;  dh[10] += dp * wc.z;
        }
    }

    float gx = dh[8], gy = dh[9], gz = dh[10];
#pragma unroll
    for (int k = 0; k < 8; k += 2) {
        unsigned ex = jxp[k >> 1], ey = jyp[k >> 1], ez = jzp[k >> 1];
        gx += lo2(ex) * dh[k] + hi2(ex) * dh[k + 1];
        gy += lo2(ey) * dh[k] + hi2(ey) * dh[k + 1];
        gz += lo2(ez) * dh[k] + hi2(ez) * dh[k + 1];
    }

    out[N + 3 * n + 0] = gx;
    out[N + 3 * n + 1] = gy;
    out[N + 3 * n + 2] = gz;
}

extern "C" void kernel_launch(void* const* d_in, const int* in_sizes, int n_in,
                              void* d_out, int out_size, void* d_ws, size_t ws_size,
                              hipStream_t stream) {
    const float* pos  = (const float*)d_in[0];
    const float* grid = (const float*)d_in[1];
    const float* W0   = (const float*)d_in[2];
    const float* b0   = (const float*)d_in[3];
    const float* W1   = (const float*)d_in[4];
    const float* b1   = (const float*)d_in[5];
    const float* Wo   = (const float*)d_in[6];
    const float* bo   = (const float*)d_in[7];
    float* out = (float*)d_out;
    unsigned short* ws = (unsigned short*)d_ws;
    const int N = in_sizes[0] / 3;

    prep_kernel<<<64, 256, 0, stream>>>(W1, ws);
    nsdf_main<<<N / 256, 256, 0, stream>>>(pos, grid, W0, b0, b1, Wo, bo, ws, out, N);
}

// Round 7
// 366.049 us; speedup vs baseline: 23.7404x; 1.5380x over previous
//
#include <hip/hip_runtime.h>

#define RES 128
#define HID 128
#define W0F 30.0f
#define SCALE 63.5f

typedef __bf16 bf16x8 __attribute__((ext_vector_type(8)));
typedef float f32x4 __attribute__((ext_vector_type(4)));

__device__ __forceinline__ unsigned short bf16rne(float x) {
    unsigned u = __float_as_uint(x);
    u = (u + 0x7fffu + ((u >> 16) & 1u)) >> 16;
    return (unsigned short)u;
}
__device__ __forceinline__ unsigned pk2f(float a, float b) {
    return (unsigned)bf16rne(a) | ((unsigned)bf16rne(b) << 16);
}
__device__ __forceinline__ float lo2(unsigned p) { return __uint_as_float(p << 16); }
__device__ __forceinline__ float hi2(unsigned p) { return __uint_as_float(p & 0xffff0000u); }
__device__ __forceinline__ float frombf(unsigned short h) { return __uint_as_float(((unsigned)h) << 16); }

// ---- prep: fragment-ordered bf16 weight copies in d_ws ----
// bf16-elem offsets: 0 wct(16384) | 16384 wrw(16384) | 32768 ws1(4096) |
//                    36864 ws2(4096) | 40960 wt1(2048) | 43008 wt2(2048)
// kslot convention everywhere: kslot = (lane>>4)*8 + e  (K=32 per k-step)
__global__ void prep_kernel(const float* __restrict__ W1, const float* __restrict__ W0,
                            const float* __restrict__ b0, unsigned short* __restrict__ ws) {
    int t = blockIdx.x * blockDim.x + threadIdx.x;
    if (t < 16384) {                       // W1 colT + row frags (GEMM1/GEMM2 B)
        int tile = t >> 9, lane = (t >> 3) & 63, e = t & 7;
        int hi16 = tile >> 2, ks = tile & 3;
        int koff = ks * 32 + (lane >> 4) * 8 + e;
        int noff = hi16 * 16 + (lane & 15);
        ws[t] = bf16rne(W1[koff * HID + noff]);
        ws[16384 + t] = bf16rne(W1[noff * HID + koff]);
    } else if (t < 24576) {                // W0e B-frags for pre1 (K=32, hi/lo sets)
        int t2 = t - 16384;
        int lane = (t2 >> 3) & 63, e = t2 & 7;
        int kslot = ((lane >> 4) << 3) | e;
        int nt = (t2 >> 9) & 7;
        int n = nt * 16 + (lane & 15);
        bool set1 = t2 < 4096;
        int kk = (kslot < 12) ? kslot : ((kslot >= 16 && kslot < 28) ? kslot - 16 : -1);
        unsigned short outv = 0;
        if (kk >= 0) {
            float w = (kk < 11) ? W0[kk * HID + n] : b0[n];
            unsigned short h = bf16rne(w);
            if (set1) outv = h;                       // slots 0-11: W0hi; 16-27: W0hi (pairs Xlo)
            else if (kslot < 12) outv = bf16rne(w - frombf(h));   // slots 0-11: W0lo
        }
        ws[32768 + t2] = outv;
    } else {                               // W0^T B-frags for GEMM3 (K=128, N=16, hi/lo)
        int t3 = t - 24576;
        int lane = (t3 >> 3) & 63, e = t3 & 7;
        int ksl = ((lane >> 4) << 3) | e;
        int ks = (t3 >> 9) & 3;
        int j = ks * 32 + ksl;
        int kp = lane & 15;
        unsigned short outv = 0;
        if (kp < 11) {
            float w = W0[kp * HID + j];
            unsigned short h = bf16rne(w);
            if (t3 < 2048) outv = h;
            else outv = bf16rne(w - frombf(h));
        }
        ws[40960 + t3] = outv;
    }
}

__global__ __launch_bounds__(256, 2)
void nsdf_main(const float* __restrict__ pos, const float* __restrict__ grid,
               const float* __restrict__ b1, const float* __restrict__ Wo,
               const float* __restrict__ bo, const unsigned short* __restrict__ wfrag,
               float* __restrict__ out, int N)
{
    __shared__ unsigned short sBuf[4 * 8192];   // 64 KB: 16 KB wave-private regions
    __shared__ float sB1v[HID], sWov[HID];
    __shared__ float sBo;

    const int tid = threadIdx.x;
    const int l = tid & 63;
    const int wid = tid >> 6;
    const int low = l & 15;
    const int lk = l >> 4;
    const int wb = wid * 16384;
    const int mloc = l;
    const int q15 = mloc & 15, mtOwn = mloc >> 4;

    if (tid < HID) { sB1v[tid] = b1[tid]; sWov[tid] = Wo[tid]; }
    if (tid == 0) sBo = bo[0];

    const int n = blockIdx.x * 256 + tid;
    const float px = pos[3 * n], py = pos[3 * n + 1], pz = pos[3 * n + 2];

    // ---- encode: smoothstep trilinear + Jacobian (per-thread) ----
    const float upper = 126.999992f;
    float fx = fminf(fmaxf((px + 1.f) * 0.5f * (RES - 1), 0.f), upper);
    float fy = fminf(fmaxf((py + 1.f) * 0.5f * (RES - 1), 0.f), upper);
    float fz = fminf(fmaxf((pz + 1.f) * 0.5f * (RES - 1), 0.f), upper);
    int ix0 = (int)fx, iy0 = (int)fy, iz0 = (int)fz;
    float tx = fx - (float)ix0, ty = fy - (float)iy0, tz = fz - (float)iz0;
    float wx = tx * tx * (3.f - 2.f * tx);
    float wy = ty * ty * (3.f - 2.f * ty);
    float wz = tz * tz * (3.f - 2.f * tz);
    float dwx = 6.f * tx * (1.f - tx) * SCALE;
    float dwy = 6.f * ty * (1.f - ty) * SCALE;
    float dwz = 6.f * tz * (1.f - tz) * SCALE;

    const float4* g4 = (const float4*)grid;
    int b000 = ((ix0 * RES + iy0) * RES + iz0) * 2;
    int b010 = ((ix0 * RES + (iy0 + 1)) * RES + iz0) * 2;
    int b100 = (((ix0 + 1) * RES + iy0) * RES + iz0) * 2;
    int b110 = (((ix0 + 1) * RES + (iy0 + 1)) * RES + iz0) * 2;

    float c000[8], c001[8], c010[8], c011[8], c100[8], c101[8], c110[8], c111[8];
    *(float4*)&c000[0] = g4[b000];     *(float4*)&c000[4] = g4[b000 + 1];
    *(float4*)&c001[0] = g4[b000 + 2]; *(float4*)&c001[4] = g4[b000 + 3];
    *(float4*)&c010[0] = g4[b010];     *(float4*)&c010[4] = g4[b010 + 1];
    *(float4*)&c011[0] = g4[b010 + 2]; *(float4*)&c011[4] = g4[b010 + 3];
    *(float4*)&c100[0] = g4[b100];     *(float4*)&c100[4] = g4[b100 + 1];
    *(float4*)&c101[0] = g4[b100 + 2]; *(float4*)&c101[4] = g4[b100 + 3];
    *(float4*)&c110[0] = g4[b110];     *(float4*)&c110[4] = g4[b110 + 1];
    *(float4*)&c111[0] = g4[b110 + 2]; *(float4*)&c111[4] = g4[b110 + 3];

    float emb[8];
    unsigned jxp[4], jyp[4], jzp[4];
#pragma unroll
    for (int k = 0; k < 8; k += 2) {
        float ex[2], ey[2], ez[2];
#pragma unroll
        for (int qq = 0; qq < 2; ++qq) {
            int kk = k + qq;
            float a000 = c000[kk], a001 = c001[kk], a010 = c010[kk], a011 = c011[kk];
            float a100 = c100[kk], a101 = c101[kk], a110 = c110[kk], a111 = c111[kk];
            float dX00 = a100 - a000, dX10 = a110 - a010;
            float dX01 = a101 - a001, dX11 = a111 - a011;
            float c00 = a000 + dX00 * wx;
            float c10 = a010 + dX10 * wx;
            float c01 = a001 + dX01 * wx;
            float c11 = a011 + dX11 * wx;
            float cy0 = c00 + (c10 - c00) * wy;
            float cy1 = c01 + (c11 - c01) * wy;
            emb[kk] = cy0 + (cy1 - cy0) * wz;
            ez[qq] = (cy1 - cy0) * dwz;
            float dy0 = c10 - c00, dy1 = c11 - c01;
            ey[qq] = (dy0 + (dy1 - dy0) * wz) * dwy;
            float dx0 = dX00 + (dX10 - dX00) * wy;
            float dx1 = dX01 + (dX11 - dX01) * wy;
            ex[qq] = (dx0 + (dx1 - dx0) * wz) * dwx;
        }
        jxp[k >> 1] = pk2f(ex[0], ex[1]);
        jyp[k >> 1] = pk2f(ey[0], ey[1]);
        jzp[k >> 1] = pk2f(ez[0], ez[1]);
    }

    __syncthreads();

    // ---- stage X = [emb8, px,py,pz, 1] hi/lo-split into A-frag layout ----
    {
        float xv[12];
#pragma unroll
        for (int k = 0; k < 8; ++k) xv[k] = emb[k];
        xv[8] = px; xv[9] = py; xv[10] = pz; xv[11] = 1.f;
        unsigned hw[6], lw[6];
#pragma unroll
        for (int kk = 0; kk < 6; ++kk) {
            float a = xv[2 * kk], b = xv[2 * kk + 1];
            unsigned short ha = bf16rne(a), hb = bf16rne(b);
            hw[kk] = (unsigned)ha | ((unsigned)hb << 16);
            lw[kk] = pk2f(a - frombf(ha), b - frombf(hb));
        }
        int base = wb + q15 * 256 + mtOwn * 64;
        int sw = (mloc & 7) << 4;
        uint4 ch;
        ch.x = hw[0]; ch.y = hw[1]; ch.z = hw[2]; ch.w = hw[3];
        *(uint4*)((char*)sBuf + ((base + 0) ^ sw)) = ch;          // kslot 0-7 (hi)
        ch.x = hw[4]; ch.y = hw[5]; ch.z = 0u; ch.w = 0u;
        *(uint4*)((char*)sBuf + ((base + 16) ^ sw)) = ch;         // kslot 8-15
        ch.x = lw[0]; ch.y = lw[1]; ch.z = lw[2]; ch.w = lw[3];
        *(uint4*)((char*)sBuf + ((base + 32) ^ sw)) = ch;         // kslot 16-23 (lo)
        ch.x = lw[4]; ch.y = lw[5]; ch.z = 0u; ch.w = 0u;
        *(uint4*)((char*)sBuf + ((base + 48) ^ sw)) = ch;         // kslot 24-31
    }

    // ---- X A-frags to registers (kept live through backward) ----
    uint4 XF[4];
#pragma unroll
    for (int mt = 0; mt < 4; ++mt) {
        int byte = (wb + low * 256 + mt * 64 + lk * 16) ^ ((low & 7) << 4);
        XF[mt] = *(const uint4*)((const char*)sBuf + byte);
    }

    const uint4* wct = (const uint4*)(wfrag);
    const uint4* wrw = (const uint4*)(wfrag + 16384);
    const uint4* ws1 = (const uint4*)(wfrag + 32768);
    const uint4* ws2 = (const uint4*)(wfrag + 36864);
    const uint4* wt1 = (const uint4*)(wfrag + 40960);
    const uint4* wt2 = (const uint4*)(wfrag + 43008);

    // ---- layer 1 fwd via MFMA: pre1 = X@W0e (hi/lo), h1 = sin(30*pre1) ----
#pragma unroll 1
    for (int nt = 0; nt < 8; ++nt) {
        uint4 B1 = ws1[nt * 64 + l];
        uint4 B2 = ws2[nt * 64 + l];
        f32x4 p[4];
#pragma unroll
        for (int mt = 0; mt < 4; ++mt) p[mt] = (f32x4){0.f, 0.f, 0.f, 0.f};
#pragma unroll
        for (int mt = 0; mt < 4; ++mt) {
            p[mt] = __builtin_amdgcn_mfma_f32_16x16x32_bf16(
                __builtin_bit_cast(bf16x8, XF[mt]), __builtin_bit_cast(bf16x8, B1), p[mt], 0, 0, 0);
            p[mt] = __builtin_amdgcn_mfma_f32_16x16x32_bf16(
                __builtin_bit_cast(bf16x8, XF[mt]), __builtin_bit_cast(bf16x8, B2), p[mt], 0, 0, 0);
        }
        int cbase = ((nt & 1) * 2 + (low >> 3)) * 16 + (low & 7) * 2;
#pragma unroll
        for (int mt = 0; mt < 4; ++mt)
#pragma unroll
            for (int r = 0; r < 4; ++r) {
                float s = __sinf(W0F * p[mt][r]);
                int q = lk * 4 + r;
                int byte = (wb + (nt >> 1) * 4096 + q * 256 + mt * 64 + cbase) ^ ((q & 7) << 4);
                sBuf[byte >> 1] = bf16rne(s);
            }
    }

    // ---- GEMM1: pre2 = h1 @ W1, streamed; v-phase per tile ----
    uint4 A1[4][4];
#pragma unroll
    for (int mt = 0; mt < 4; ++mt)
#pragma unroll
        for (int js = 0; js < 4; ++js) {
            int byte = (wb + js * 4096 + low * 256 + mt * 64 + lk * 16) ^ ((low & 7) << 4);
            A1[mt][js] = *(const uint4*)((const char*)sBuf + byte);
        }

    float sdfp[4][4];
#pragma unroll
    for (int a = 0; a < 4; ++a)
#pragma unroll
        for (int b = 0; b < 4; ++b) sdfp[a][b] = 0.f;

#pragma unroll 1
    for (int nt = 0; nt < 8; ++nt) {
        uint4 Bf[4];
#pragma unroll
        for (int js = 0; js < 4; ++js) Bf[js] = wct[(nt * 4 + js) * 64 + l];
        f32x4 c1[4];
#pragma unroll
        for (int mt = 0; mt < 4; ++mt) c1[mt] = (f32x4){0.f, 0.f, 0.f, 0.f};
#pragma unroll
        for (int mt = 0; mt < 4; ++mt)
#pragma unroll
            for (int js = 0; js < 4; ++js)
                c1[mt] = __builtin_amdgcn_mfma_f32_16x16x32_bf16(
                    __builtin_bit_cast(bf16x8, A1[mt][js]),
                    __builtin_bit_cast(bf16x8, Bf[js]), c1[mt], 0, 0, 0);
        int i = nt * 16 + low;
        float b1e = sB1v[i], woe = sWov[i];
        int cbase = ((nt & 1) * 2 + (low >> 3)) * 16 + (low & 7) * 2;
#pragma unroll
        for (int mt = 0; mt < 4; ++mt)
#pragma unroll
            for (int r = 0; r < 4; ++r) {
                float pre = c1[mt][r] + b1e;
                float s, c;
                __sincosf(W0F * pre, &s, &c);
                sdfp[mt][r] += woe * s;
                float v = W0F * c * woe;
                int q = lk * 4 + r;
                int byte = (wb + (nt >> 1) * 4096 + q * 256 + mt * 64 + cbase) ^ ((q & 7) << 4);
                sBuf[byte >> 1] = bf16rne(v);
            }
    }

    // ---- sdf reduce + store ----
    {
        int blkBase = blockIdx.x * 256 + wid * 64;
        float boV = sBo;
#pragma unroll
        for (int mt = 0; mt < 4; ++mt)
#pragma unroll
            for (int r = 0; r < 4; ++r) {
                float sv = sdfp[mt][r];
                sv += __shfl_xor(sv, 1);
                sv += __shfl_xor(sv, 2);
                sv += __shfl_xor(sv, 4);
                sv += __shfl_xor(sv, 8);
                if (low == 0) out[blkBase + mt * 16 + lk * 4 + r] = sv + boV;
            }
    }

    // ---- fused GEMM2 + pre1-recompute + dp-scatter ----
    uint4 A2[4][4];
#pragma unroll
    for (int mt = 0; mt < 4; ++mt)
#pragma unroll
        for (int is = 0; is < 4; ++is) {
            int byte = (wb + is * 4096 + low * 256 + mt * 64 + lk * 16) ^ ((low & 7) << 4);
            A2[mt][is] = *(const uint4*)((const char*)sBuf + byte);
        }

#pragma unroll 1
    for (int jt = 0; jt < 8; ++jt) {
        uint4 Bf[4];
#pragma unroll
        for (int is = 0; is < 4; ++is) Bf[is] = wrw[(jt * 4 + is) * 64 + l];
        f32x4 c2[4];
#pragma unroll
        for (int mt = 0; mt < 4; ++mt) c2[mt] = (f32x4){0.f, 0.f, 0.f, 0.f};
#pragma unroll
        for (int mt = 0; mt < 4; ++mt)
#pragma unroll
            for (int is = 0; is < 4; ++is)
                c2[mt] = __builtin_amdgcn_mfma_f32_16x16x32_bf16(
                    __builtin_bit_cast(bf16x8, A2[mt][is]),
                    __builtin_bit_cast(bf16x8, Bf[is]), c2[mt], 0, 0, 0);
        uint4 B1 = ws1[jt * 64 + l];
        uint4 B2 = ws2[jt * 64 + l];
        f32x4 p[4];
#pragma unroll
        for (int mt = 0; mt < 4; ++mt) p[mt] = (f32x4){0.f, 0.f, 0.f, 0.f};
#pragma unroll
        for (int mt = 0; mt < 4; ++mt) {
            p[mt] = __builtin_amdgcn_mfma_f32_16x16x32_bf16(
                __builtin_bit_cast(bf16x8, XF[mt]), __builtin_bit_cast(bf16x8, B1), p[mt], 0, 0, 0);
            p[mt] = __builtin_amdgcn_mfma_f32_16x16x32_bf16(
                __builtin_bit_cast(bf16x8, XF[mt]), __builtin_bit_cast(bf16x8, B2), p[mt], 0, 0, 0);
        }
        int cbase = ((jt & 1) * 2 + (low >> 3)) * 16 + (low & 7) * 2;
#pragma unroll
        for (int mt = 0; mt < 4; ++mt)
#pragma unroll
            for (int r = 0; r < 4; ++r) {
                float dp = W0F * __cosf(W0F * p[mt][r]) * c2[mt][r];
                int q = lk * 4 + r;
                int byte = (wb + (jt >> 1) * 4096 + q * 256 + mt * 64 + cbase) ^ ((q & 7) << 4);
                sBuf[byte >> 1] = bf16rne(dp);
            }
    }

    // ---- GEMM3: dh = dp @ W0e^T (hi/lo), then scatter [m][k'] fp32 ----
    uint4 A3[4][4];
#pragma unroll
    for (int mt = 0; mt < 4; ++mt)
#pragma unroll
        for (int ks = 0; ks < 4; ++ks) {
            int byte = (wb + ks * 4096 + low * 256 + mt * 64 + lk * 16) ^ ((low & 7) << 4);
            A3[mt][ks] = *(const uint4*)((const char*)sBuf + byte);
        }
    {
        f32x4 d[4];
#pragma unroll
        for (int mt = 0; mt < 4; ++mt) d[mt] = (f32x4){0.f, 0.f, 0.f, 0.f};
#pragma unroll
        for (int ks = 0; ks < 4; ++ks) {
            uint4 B1 = wt1[ks * 64 + l];
            uint4 B2 = wt2[ks * 64 + l];
#pragma unroll
            for (int mt = 0; mt < 4; ++mt) {
                d[mt] = __builtin_amdgcn_mfma_f32_16x16x32_bf16(
                    __builtin_bit_cast(bf16x8, A3[mt][ks]), __builtin_bit_cast(bf16x8, B1), d[mt], 0, 0, 0);
                d[mt] = __builtin_amdgcn_mfma_f32_16x16x32_bf16(
                    __builtin_bit_cast(bf16x8, A3[mt][ks]), __builtin_bit_cast(bf16x8, B2), d[mt], 0, 0, 0);
            }
        }
        // scatter dh[m][k'=low] fp32 into [m][16] rows (XOR on 16B blocks)
#pragma unroll
        for (int mt = 0; mt < 4; ++mt)
#pragma unroll
            for (int r = 0; r < 4; ++r) {
                int m = mt * 16 + lk * 4 + r;
                int byte = wb + m * 64 + ((low << 2) ^ (lk << 4));
                *(float*)((char*)sBuf + byte) = d[mt][r];
            }
    }

    // ---- per-thread: read own dh row, combine with Jacobian ----
    {
        int s = (mloc >> 2) & 3;
        int rb = wb + mloc * 64;
        float4 d0 = *(const float4*)((const char*)sBuf + rb + ((0x00 ^ (s << 4))));
        float4 d1 = *(const float4*)((const char*)sBuf + rb + ((0x10 ^ (s << 4))));
        float4 d2 = *(const float4*)((const char*)sBuf + rb + ((0x20 ^ (s << 4))));
        float gx = d2.x, gy = d2.y, gz = d2.z;
        float dhv[8] = {d0.x, d0.y, d0.z, d0.w, d1.x, d1.y, d1.z, d1.w};
#pragma unroll
        for (int k = 0; k < 8; k += 2) {
            unsigned ex = jxp[k >> 1], ey = jyp[k >> 1], ez = jzp[k >> 1];
            gx += lo2(ex) * dhv[k] + hi2(ex) * dhv[k + 1];
            gy += lo2(ey) * dhv[k] + hi2(ey) * dhv[k + 1];
            gz += lo2(ez) * dhv[k] + hi2(ez) * dhv[k + 1];
        }
        out[N + 3 * n + 0] = gx;
        out[N + 3 * n + 1] = gy;
        out[N + 3 * n + 2] = gz;
    }
}

extern "C" void kernel_launch(void* const* d_in, const int* in_sizes, int n_in,
                              void* d_out, int out_size, void* d_ws, size_t ws_size,
                              hipStream_t stream) {
    const float* pos  = (const float*)d_in[0];
    const float* grid = (const float*)d_in[1];
    const float* W0   = (const float*)d_in[2];
    const float* b0   = (const float*)d_in[3];
    const float* W1   = (const float*)d_in[4];
    const float* b1   = (const float*)d_in[5];
    const float* Wo   = (const float*)d_in[6];
    const float* bo   = (const float*)d_in[7];
    float* out = (float*)d_out;
    unsigned short* ws = (unsigned short*)d_ws;
    const int N = in_sizes[0] / 3;

    prep_kernel<<<112, 256, 0, stream>>>(W1, W0, b0, ws);
    nsdf_main<<<N / 256, 256, 0, stream>>>(pos, grid, b1, Wo, bo, ws, out, N);
}